// Round 1
// 236.692 us; speedup vs baseline: 1.0878x; 1.0878x over previous
//
#include <hip/hip_runtime.h>

// Self-attention forward. Inputs f32: x[4,2048,1024], Wqkv[1024,3072],
// bqkv[3072], Wout[1024,1024], bout[1024]; mask[4,2048,2048] int32.
// Output f32 [4,2048,1024].
//
// Round-7 change: K1 (QKV proj) and K2 (QK^T) move from the 128x128
// 2-barrier gemm128 (573 TF, MfmaUtil 24%, 1.9e7 LDS bank conflicts) to a
// 256x256 8-phase schedule (T1 XCD swizzle + T2 LDS XOR swizzle + T3/T4
// counted vmcnt, never 0 + T5 setprio). K4/K5 keep gemm128: their 256^2
// grids (128 wgs) would idle half the CUs at 1 block/CU.

typedef __attribute__((ext_vector_type(8))) short short8;
typedef __attribute__((ext_vector_type(4))) float f32x4;
typedef unsigned short u16;

#define SEQ 2048
#define NB 4

static __device__ __forceinline__ u16 f2bf(float f) {
    unsigned int u = __builtin_bit_cast(unsigned int, f);
    u += 0x7fffu + ((u >> 16) & 1u);   // RNE
    return (u16)(u >> 16);
}
static __device__ __forceinline__ float bf2f(u16 h) {
    unsigned int u = ((unsigned int)h) << 16;
    return __builtin_bit_cast(float, u);
}

// async global->LDS, 16 bytes/lane. LDS dest = wave-uniform base + lane*16.
static __device__ __forceinline__ void gld16(const u16* l, const u16* g) {
    __builtin_amdgcn_global_load_lds(
        (__attribute__((address_space(1))) void*)(g),
        (__attribute__((address_space(3))) void*)(l),
        16, 0, 0);
}

// f32 -> bf16, 8 elems/thread.
__global__ __launch_bounds__(256) void cvt_bf16(const float* __restrict__ s,
                                                u16* __restrict__ d, long n) {
    long i = ((long)blockIdx.x * 256 + threadIdx.x) * 8;
    if (i >= n) return;
    f32x4 a = *(const f32x4*)(s + i);
    f32x4 b = *(const f32x4*)(s + i + 4);
    short8 o;
    o[0] = (short)f2bf(a.x); o[1] = (short)f2bf(a.y);
    o[2] = (short)f2bf(a.z); o[3] = (short)f2bf(a.w);
    o[4] = (short)f2bf(b.x); o[5] = (short)f2bf(b.y);
    o[6] = (short)f2bf(b.z); o[7] = (short)f2bf(b.w);
    *(short8*)(d + i) = o;
}

// f32 [R][C] -> bf16 [C][R] (transpose + convert), 32x32 LDS tiles.
__global__ __launch_bounds__(256) void transpose_cvt(const float* __restrict__ in,
                                                     u16* __restrict__ out,
                                                     int R, int C) {
    __shared__ float t[32][33];
    const int c0 = blockIdx.x * 32;
    const int r0 = blockIdx.y * 32;
    const int x = threadIdx.x & 31;
    const int y = (threadIdx.x >> 5) * 4;
    #pragma unroll
    for (int i = 0; i < 4; i++)
        t[y + i][x] = in[(long)(r0 + y + i) * C + c0 + x];
    __syncthreads();
    #pragma unroll
    for (int i = 0; i < 4; i++)
        out[(long)(c0 + y + i) * R + r0 + x] = f2bf(t[x][y + i]);
}

// V slice of qkv (per batch [2048 s][1024 d], row stride 3072, col offset 2048)
// -> vt [b][1024 d][2048 s]. bf16 32x32 tile transpose.
__global__ __launch_bounds__(256) void transpose_v(const u16* __restrict__ qkv,
                                                   u16* __restrict__ vt) {
    __shared__ u16 t[32][33];
    const int b = blockIdx.z;
    const int s0 = blockIdx.y * 32;
    const int d0 = blockIdx.x * 32;
    const int x = threadIdx.x & 31;
    const int y = (threadIdx.x >> 5) * 4;
    const u16* src = qkv + (long)b * SEQ * 3072 + 2048;
    u16* dst = vt + (long)b * 1024 * SEQ;
    #pragma unroll
    for (int i = 0; i < 4; i++)
        t[y + i][x] = src[(long)(s0 + y + i) * 3072 + d0 + x];
    __syncthreads();
    #pragma unroll
    for (int i = 0; i < 4; i++)
        dst[(long)(d0 + y + i) * SEQ + s0 + x] = t[x][y + i];
}

// ============================ gemm256 ======================================
// 256x256 tile, BK=64, 512 threads = 8 waves (2M x 4N), per-wave 128x64 out
// = acc[8][4] f32x4. C[m][n] = sum_k A[m][k]*B[n][k] (B is [N][K] row-major).
//
// LDS 128 KiB: lds[2 dbuf][4 regions][8192 u16]. Regions (each 128 "region
// rows" x 64 k, 16 KiB):
//   0 = A-lo : tile rows {wm*128 + [0,64)}   (mh=0 frags of both wave-rows)
//   1 = A-hi : tile rows {wm*128 + [64,128)} (mh=1)
//   2 = B-lo : tile cols {wn*64 + [0,32)}    (nh=0)
//   3 = B-hi : tile cols {wn*64 + [32,64)}   (nh=1)
// T2 swizzle within a region: 16-B slot index ^= (region_row & 7); applied
// on the READ address and as pre-swizzled GLOBAL source col on the stage
// (global_load_lds writes linearly: wave base + lane*16).
//
// Phase schedule per K-tile t (buf = t&1, nb = buf^1), quadrants
// (m0n0),(m0n1),(m1n0),(m1n1); B-frags held in regs q0->q2 / q1->q3:
//   q0: ds_read A-lo(12.. 8) + B-lo(4); stage B-hi(t+1)->[nb][3]; bar;
//       lgkm0; prio1; 16 mfma (0,0); prio0; bar
//   q1: ds_read B-hi(4);              stage A-hi(t+1)->[nb][1]; vmcnt(6);
//       bar; lgkm0; prio1; 16 mfma (0,1); prio0; bar
//   q2: ds_read A-hi(8);              stage A-lo(t+2)->[buf][0]; bar;
//       lgkm0; prio1; 16 mfma (1,0); prio0; bar
//   q3: (no reads)                    stage B-lo(t+2)->[buf][2]; vmcnt(6);
//       bar; lgkm0; prio1; 16 mfma (1,1); prio0; bar
// Ledger: every region's stage-issue is >= 4 phases before its first read
// and covered by an intervening vmcnt(6)+barrier (A-lo/B-lo: staged
// q2/q3(t-2), covered long before q0(t); B-hi(t): staged q0(t-1), 4th-newest
// at q3(t-1)'s vmcnt(6); A-hi(t): staged q1(t-1), 2nd-oldest at q1(t)'s
// vmcnt(6), read q2(t)). Overwrites land >= 1 barrier-pair after the
// region's last ds_read (A-lo read q0 only, overwritten q2; B-lo read q0,
// overwritten q3; cross-buffer stages trail the other tile's reads by >= 2
// phases). Tail: stage k-offset clamped to (t-2) -- same parity/region,
// data never read. Prologue = steady-state phases -6..-1 + vmcnt(6).
template<int EPI>
__global__ __launch_bounds__(512) void gemm256(
    const u16* __restrict__ Ap, long lda, long aBatch,
    const u16* __restrict__ Bp, long ldb, long bBatch,
    void* __restrict__ Cp, long ldc, long cBatch,
    const float* __restrict__ bias, float scale, int K, int nbx)
{
    __shared__ __attribute__((aligned(16))) u16 lds[2][4][8192];

    const int T = K >> 6;
    const int tid = threadIdx.x;
    const int lane = tid & 63;
    const int wave = tid >> 6;
    const int wm = wave >> 2;          // 0..1
    const int wn = wave & 3;           // 0..3
    const int m16 = lane & 15;
    const int quad = lane >> 4;
    const int b = blockIdx.z;

    // T1: bijective XCD swizzle (nwg % 8 == 0 for all launches here)
    const int nwg = gridDim.x;
    int wg = blockIdx.x;
    if ((nwg & 7) == 0)
        wg = (wg & 7) * (nwg >> 3) + (wg >> 3);
    const int bx = wg % nbx;
    const int by = wg / nbx;
    const long gm0 = (long)by * 256;
    const long gn0 = (long)bx * 256;

    const u16* A = Ap + (long)b * aBatch;
    const u16* B = Bp + (long)b * bBatch;

    // staging thread constants. Region row r = (i*8+wave)*8 + rl, r&7 == rl.
    const int rl = lane >> 3;                    // 0..7
    const int lsl = ((lane & 7) ^ rl) * 8;       // pre-swizzled src col (u16)
    const long aR = gm0 + wave * 8 + rl;         // + i*128 + h*64
    const long bR = gn0 + (wave >> 2) * 64 + (wave & 3) * 8 + rl; // + i*128 + h*32

#define STG_A(bufi, h, tt) do { \
    const long kc_ = (long)((((tt) < T) ? (tt) : (tt) - 2) << 6); \
    gld16(&lds[bufi][h][wave * 512],       A + (aR + (h) * 64) * lda + kc_ + lsl); \
    gld16(&lds[bufi][h][(8 + wave) * 512], A + (aR + 128 + (h) * 64) * lda + kc_ + lsl); \
} while (0)
#define STG_B(bufi, h, tt) do { \
    const long kc_ = (long)((((tt) < T) ? (tt) : (tt) - 2) << 6); \
    gld16(&lds[bufi][2 + (h)][wave * 512],       B + (bR + (h) * 32) * ldb + kc_ + lsl); \
    gld16(&lds[bufi][2 + (h)][(8 + wave) * 512], B + (bR + 128 + (h) * 32) * ldb + kc_ + lsl); \
} while (0)

    // read offsets (u16). A region row = wm*64 + mfl*16 + m16; B row =
    // wn*32 + nj*16 + m16; slot = ks*4+quad, swizzled ^= (m16&7).
    const int s0 = quad ^ (m16 & 7);
    const int aBase = (wm * 64 + m16) * 64;
    const int bBase = (wn * 32 + m16) * 64;
    const int aoff0 = aBase + s0 * 8, aoff1 = aBase + (s0 ^ 4) * 8;
    const int boff0 = bBase + s0 * 8, boff1 = bBase + (s0 ^ 4) * 8;

    short8 aF[4][2], b0F[2][2], b1F[2][2];
    f32x4 acc[8][4];
    #pragma unroll
    for (int mi = 0; mi < 8; mi++)
        #pragma unroll
        for (int ni = 0; ni < 4; ni++)
            acc[mi][ni] = (f32x4){0.f, 0.f, 0.f, 0.f};

#define LD_A(bufi, h) do { \
    const u16* p_ = &lds[bufi][h][0]; \
    _Pragma("unroll") \
    for (int mfl_ = 0; mfl_ < 4; ++mfl_) { \
        aF[mfl_][0] = *(const short8*)(p_ + aoff0 + mfl_ * 1024); \
        aF[mfl_][1] = *(const short8*)(p_ + aoff1 + mfl_ * 1024); \
    } \
} while (0)
#define LD_B(bufi, h, BF) do { \
    const u16* p_ = &lds[bufi][2 + (h)][0]; \
    _Pragma("unroll") \
    for (int nj_ = 0; nj_ < 2; ++nj_) { \
        BF[nj_][0] = *(const short8*)(p_ + boff0 + nj_ * 1024); \
        BF[nj_][1] = *(const short8*)(p_ + boff1 + nj_ * 1024); \
    } \
} while (0)
#define MFMAQ(mh, nh, BF) do { \
    _Pragma("unroll") \
    for (int mi_ = 0; mi_ < 4; ++mi_) \
    _Pragma("unroll") \
    for (int nj_ = 0; nj_ < 2; ++nj_) { \
        acc[(mh)*4+mi_][(nh)*2+nj_] = __builtin_amdgcn_mfma_f32_16x16x32_bf16( \
            aF[mi_][0], BF[nj_][0], acc[(mh)*4+mi_][(nh)*2+nj_], 0, 0, 0); \
        acc[(mh)*4+mi_][(nh)*2+nj_] = __builtin_amdgcn_mfma_f32_16x16x32_bf16( \
            aF[mi_][1], BF[nj_][1], acc[(mh)*4+mi_][(nh)*2+nj_], 0, 0, 0); \
    } \
} while (0)
#define BAR() __builtin_amdgcn_s_barrier()
#define LGKM0() asm volatile("s_waitcnt lgkmcnt(0)" ::: "memory")
#define VM6() asm volatile("s_waitcnt vmcnt(6)" ::: "memory")

    // prologue: steady-state stage phases -6..-1
    STG_A(0, 0, 0);          // A-lo(0)
    STG_B(0, 0, 0);          // B-lo(0)
    STG_B(0, 1, 0);          // B-hi(0)
    STG_A(0, 1, 0);          // A-hi(0)
    STG_A(1, 0, 1);          // A-lo(1)
    STG_B(1, 0, 1);          // B-lo(1)
    VM6();                   // tile-0 A-lo/B-lo/B-hi landed
    BAR();

    for (int t = 0; t < T; ++t) {
        const int buf = t & 1, nb = buf ^ 1;
        // ---- q0: quadrant (m0,n0)
        LD_A(buf, 0);
        LD_B(buf, 0, b0F);
        STG_B(nb, 1, t + 1);
        BAR(); LGKM0();
        __builtin_amdgcn_s_setprio(1);
        MFMAQ(0, 0, b0F);
        __builtin_amdgcn_s_setprio(0);
        BAR();
        // ---- q1: quadrant (m0,n1)
        LD_B(buf, 1, b1F);
        STG_A(nb, 1, t + 1);
        VM6();
        BAR(); LGKM0();
        __builtin_amdgcn_s_setprio(1);
        MFMAQ(0, 1, b1F);
        __builtin_amdgcn_s_setprio(0);
        BAR();
        // ---- q2: quadrant (m1,n0)  (b0F reused from q0)
        LD_A(buf, 1);
        STG_A(buf, 0, t + 2);
        BAR(); LGKM0();
        __builtin_amdgcn_s_setprio(1);
        MFMAQ(1, 0, b0F);
        __builtin_amdgcn_s_setprio(0);
        BAR();
        // ---- q3: quadrant (m1,n1)  (aF from q2, b1F from q1)
        STG_B(buf, 0, t + 2);
        VM6();
        BAR(); LGKM0();
        __builtin_amdgcn_s_setprio(1);
        MFMAQ(1, 1, b1F);
        __builtin_amdgcn_s_setprio(0);
        BAR();
    }

    // C-write. Frag (mi,ni): rows gm0+wm*128+(mi>>2)*64+(mi&3)*16+quad*4+r,
    // col gn0+wn*64+(ni>>1)*32+(ni&1)*16+m16.
    const long row0 = gm0 + wm * 128 + quad * 4;
    if (EPI == 0 || EPI == 1) {
        u16* C = (u16*)Cp + (long)b * cBatch;
        #pragma unroll
        for (int ni = 0; ni < 4; ++ni) {
            const long col = gn0 + wn * 64 + (ni >> 1) * 32 + (ni & 1) * 16 + m16;
            const float bv = (EPI == 0 && bias) ? bias[col] : 0.f;
            #pragma unroll
            for (int mi = 0; mi < 8; ++mi) {
                const long rb = row0 + (mi >> 2) * 64 + (mi & 3) * 16;
                #pragma unroll
                for (int r = 0; r < 4; ++r) {
                    const float vv = (EPI == 1) ? acc[mi][ni][r] * scale
                                                : acc[mi][ni][r] + bv;
                    C[(rb + r) * ldc + col] = f2bf(vv);
                }
            }
        }
    } else {
        float* C = (float*)Cp + (long)b * cBatch;
        #pragma unroll
        for (int ni = 0; ni < 4; ++ni) {
            const long col = gn0 + wn * 64 + (ni >> 1) * 32 + (ni & 1) * 16 + m16;
            const float bv = bias ? bias[col] : 0.f;
            #pragma unroll
            for (int mi = 0; mi < 8; ++mi) {
                const long rb = row0 + (mi >> 2) * 64 + (mi & 3) * 16;
                #pragma unroll
                for (int r = 0; r < 4; ++r)
                    C[(rb + r) * ldc + col] = acc[mi][ni][r] + bv;
            }
        }
    }
#undef STG_A
#undef STG_B
#undef LD_A
#undef LD_B
#undef MFMAQ
#undef BAR
#undef LGKM0
#undef VM6
}

// bf16 MFMA GEMM, 128x128 tile, BK=64 (kept for K4/K5 whose 256^2 grids
// would only fill half the CUs at 1 block/CU).
template<int EPI>
__global__ __launch_bounds__(256) void gemm128(
    const u16* __restrict__ Ap, long lda, long aBatch,
    const u16* __restrict__ Bp, long ldb, long bBatch,
    void* __restrict__ Cp, long ldc, long cBatch,
    const float* __restrict__ bias,
    float scale, int K)
{
    __shared__ __attribute__((aligned(16))) u16 As[128 * 64];
    __shared__ __attribute__((aligned(16))) u16 Bs[128 * 64];

    const int tid = threadIdx.x;
    const int lane = tid & 63;
    const int wave = tid >> 6;
    const int b = blockIdx.z;
    const long m0 = (long)blockIdx.y * 128;
    const long n0 = (long)blockIdx.x * 128;

    const u16* A = Ap + (long)b * aBatch;
    const u16* B = Bp + (long)b * bBatch;

    const int wm = (wave >> 1) * 64;
    const int wn = (wave & 1) * 64;
    const int m16 = lane & 15;
    const int quad = lane >> 4;

    const int srow = lane >> 3;
    const int skk = (lane & 7) * 8;

    f32x4 acc[4][4];
    #pragma unroll
    for (int mi = 0; mi < 4; mi++)
        #pragma unroll
        for (int ni = 0; ni < 4; ni++)
            acc[mi][ni] = (f32x4){0.f, 0.f, 0.f, 0.f};

    for (int k0 = 0; k0 < K; k0 += 64) {
        #pragma unroll
        for (int c = 0; c < 4; c++) {
            const int r = wave * 32 + c * 8 + srow;
            gld16(As + (wave * 4 + c) * 512, A + (m0 + r) * lda + k0 + skk);
            gld16(Bs + (wave * 4 + c) * 512, B + (n0 + r) * ldb + k0 + skk);
        }
        __syncthreads();

        #pragma unroll
        for (int ks = 0; ks < 2; ks++) {
            short8 af[4], bf[4];
            #pragma unroll
            for (int i = 0; i < 4; i++) {
                af[i] = *(const short8*)&As[(wm + i * 16 + m16) * 64 + ks * 32 + quad * 8];
                bf[i] = *(const short8*)&Bs[(wn + i * 16 + m16) * 64 + ks * 32 + quad * 8];
            }
            #pragma unroll
            for (int mi = 0; mi < 4; mi++)
                #pragma unroll
                for (int ni = 0; ni < 4; ni++)
                    acc[mi][ni] = __builtin_amdgcn_mfma_f32_16x16x32_bf16(
                        af[mi], bf[ni], acc[mi][ni], 0, 0, 0);
        }
        __syncthreads();
    }

    const long row_base = m0 + wm + quad * 4;
    if (EPI == 0) {
        u16* C = (u16*)Cp + (long)b * cBatch;
        #pragma unroll
        for (int ni = 0; ni < 4; ni++) {
            const long col = n0 + wn + ni * 16 + m16;
            const float bv = bias ? bias[col] : 0.f;
            #pragma unroll
            for (int mi = 0; mi < 4; mi++)
                #pragma unroll
                for (int r = 0; r < 4; r++)
                    C[(row_base + mi * 16 + r) * ldc + col] = f2bf(acc[mi][ni][r] + bv);
        }
    } else if (EPI == 1) {
        u16* C = (u16*)Cp + (long)b * cBatch;
        #pragma unroll
        for (int ni = 0; ni < 4; ni++) {
            const long col = n0 + wn + ni * 16 + m16;
            #pragma unroll
            for (int mi = 0; mi < 4; mi++)
                #pragma unroll
                for (int r = 0; r < 4; r++)
                    C[(row_base + mi * 16 + r) * ldc + col] = f2bf(acc[mi][ni][r] * scale);
        }
    } else {
        float* C = (float*)Cp + (long)b * cBatch;
        #pragma unroll
        for (int ni = 0; ni < 4; ni++) {
            const long col = n0 + wn + ni * 16 + m16;
            const float bv = bias ? bias[col] : 0.f;
            #pragma unroll
            for (int mi = 0; mi < 4; mi++)
                #pragma unroll
                for (int r = 0; r < 4; r++)
                    C[(row_base + mi * 16 + r) * ldc + col] = acc[mi][ni][r] + bv;
        }
    }
}

// in-place masked row softmax over 2048 bf16 (f32 math). 1 block per row.
// mask==0 -> score := 1e-10 (applied here in f32; coalesced uint4 reads).
__global__ __launch_bounds__(256) void softmax2048(u16* __restrict__ S,
                                                   const int* __restrict__ mask) {
    const long row = blockIdx.x;
    u16* p = S + row * SEQ;
    const int* mrow = mask + row * SEQ;
    const int tid = threadIdx.x;

    short8 v = *(const short8*)(p + tid * 8);
    uint4 mw0 = *(const uint4*)(mrow + tid * 8);
    uint4 mw1 = *(const uint4*)(mrow + tid * 8 + 4);
    const unsigned int* mwv = (const unsigned int*)&mw0;

    float f[8];
    #pragma unroll
    for (int j = 0; j < 8; j++) {
        const unsigned int mv = (j < 4) ? mwv[j] : ((const unsigned int*)&mw1)[j - 4];
        f[j] = (mv == 0u) ? 1e-10f : bf2f((u16)v[j]);
    }

    float m = f[0];
    #pragma unroll
    for (int j = 1; j < 8; j++) m = fmaxf(m, f[j]);
    #pragma unroll
    for (int i = 1; i < 64; i <<= 1) m = fmaxf(m, __shfl_xor(m, i));

    __shared__ float redm[4], reds[4];
    if ((tid & 63) == 0) redm[tid >> 6] = m;
    __syncthreads();
    m = fmaxf(fmaxf(redm[0], redm[1]), fmaxf(redm[2], redm[3]));

    float e[8], s = 0.f;
    #pragma unroll
    for (int j = 0; j < 8; j++) { e[j] = __expf(f[j] - m); s += e[j]; }
    #pragma unroll
    for (int i = 1; i < 64; i <<= 1) s += __shfl_xor(s, i);
    if ((tid & 63) == 0) reds[tid >> 6] = s;
    __syncthreads();
    s = reds[0] + reds[1] + reds[2] + reds[3];

    const float inv = 1.f / s;
    short8 o;
    #pragma unroll
    for (int j = 0; j < 8; j++) o[j] = (short)f2bf(e[j] * inv);
    *(short8*)(p + tid * 8) = o;
}

extern "C" void kernel_launch(void* const* d_in, const int* in_sizes, int n_in,
                              void* d_out, int out_size, void* d_ws, size_t ws_size,
                              hipStream_t stream) {
    const float* x    = (const float*)d_in[0];
    const int*   mask = (const int*)d_in[1];
    const float* Wqkv = (const float*)d_in[2];
    const float* bqkv = (const float*)d_in[3];
    const float* Wout = (const float*)d_in[4];
    const float* bout = (const float*)d_in[5];
    float* out = (float*)d_out;

    char* ws = (char*)d_ws;
    // ws layout, total 102,760,448 bytes:
    //   [0,        16777216) xh  bf16 [8192][1024]          (cvt -> K1)
    //   [16777216, 23068672) wqt bf16 [3072][1024]          (cvt -> K1)
    //   [0,        33554432) sc  bf16 [4][2048][2048]       (K2 -> K4; xh,wqt dead)
    //   [33554432, 35651584) wot bf16 [1024][1024]          (cvt -> K5)
    //   [35651584, 85983232) qkv bf16 [8192][3072]          (K1 -> K2)
    //   [35651584, 52428800) attn bf16 [8192][1024]         (K4 -> K5; qkv dead)
    //   [85983232,102760448) vt  bf16 [4][1024][2048]       (transpose_v -> K4)
    u16* xh   = (u16*)(ws + 0);
    u16* wqt  = (u16*)(ws + 16777216);
    u16* sc   = (u16*)(ws + 0);
    u16* wot  = (u16*)(ws + 33554432);
    u16* qkv  = (u16*)(ws + 35651584);
    u16* attn = (u16*)(ws + 35651584);
    u16* vt   = (u16*)(ws + 85983232);

    cvt_bf16<<<4096, 256, 0, stream>>>(x, xh, 8388608);
    transpose_cvt<<<dim3(96, 32), 256, 0, stream>>>(Wqkv, wqt, 1024, 3072);
    transpose_cvt<<<dim3(32, 32), 256, 0, stream>>>(Wout, wot, 1024, 1024);

    // K1: qkv = x @ Wqkv + bqkv   (M=8192, N=3072, K=1024), bf16 out.
    // 256^2 8-phase: grid 12x32 = 384 wgs, nbx = 12.
    gemm256<0><<<dim3(384, 1, 1), 512, 0, stream>>>(
        xh, 1024, 0, wqt, 1024, 0, qkv, 3072, 0, bqkv, 1.f, 1024, 12);

    // V slice -> vt [b][d][s]
    transpose_v<<<dim3(32, 64, NB), 256, 0, stream>>>(qkv, vt);

    // K2: sc[b] = (Q[b] @ K[b]^T)/32   (M=N=2048, K=1024), bf16 out.
    // 256^2 8-phase: 8x8 = 64 wgs/batch x 4 = 256 = exactly 1 block/CU.
    gemm256<1><<<dim3(64, 1, NB), 512, 0, stream>>>(
        qkv, 3072, (long)SEQ * 3072, qkv + 1024, 3072, (long)SEQ * 3072,
        sc, SEQ, (long)SEQ * SEQ, nullptr, 0.03125f, 1024, 8);

    // K3: masked softmax rows (mask==0 -> 1e-10, f32 math, bf16 storage)
    softmax2048<<<dim3(NB * SEQ), 256, 0, stream>>>(sc, mask);

    // K4: attn[b] = P[b] @ V[b]   (M=2048, N=1024, K=2048), bf16 out
    gemm128<0><<<dim3(8, 16, NB), 256, 0, stream>>>(
        sc, SEQ, (long)SEQ * SEQ, vt, SEQ, (long)1024 * SEQ,
        attn, 1024, (long)SEQ * 1024, nullptr, 1.f, 2048);

    // K5: out = attn @ Wout + bout   (M=8192, N=1024, K=1024), f32 out
    gemm128<2><<<dim3(8, 64, 1), 256, 0, stream>>>(
        attn, 1024, 0, wot, 1024, 0, out, 1024, 0, bout, 1.f, 1024);
}

// Round 2
// 235.972 us; speedup vs baseline: 1.0911x; 1.0030x over previous
//
#include <hip/hip_runtime.h>

// Self-attention forward. Inputs f32: x[4,2048,1024], Wqkv[1024,3072],
// bqkv[3072], Wout[1024,1024], bout[1024]; mask[4,2048,2048] int32.
// Output f32 [4,2048,1024].
//
// Round-8 change: gemm256's vmcnt schedule deepened. Round-7 drained
// vmcnt(6) twice per K-tile, waiting on loads issued only 3 phases prior
// (exposed HBM/L2 latency twice a tile; MfmaUtil stuck at 25%). Now all
// stages are t+2-targeted at earliest-legal phases and ONE vmcnt(8) per
// tile drains loads aged 4-7 phases. Barriers cut 8/tile -> 4/tile, all
// as asm s_barrier with memory clobber (hoist safety). B-lo(t+1) read
// moved after q3's barrier to overlap the (1,1) MFMA cluster.

typedef __attribute__((ext_vector_type(8))) short short8;
typedef __attribute__((ext_vector_type(4))) float f32x4;
typedef unsigned short u16;

#define SEQ 2048
#define NB 4

static __device__ __forceinline__ u16 f2bf(float f) {
    unsigned int u = __builtin_bit_cast(unsigned int, f);
    u += 0x7fffu + ((u >> 16) & 1u);   // RNE
    return (u16)(u >> 16);
}
static __device__ __forceinline__ float bf2f(u16 h) {
    unsigned int u = ((unsigned int)h) << 16;
    return __builtin_bit_cast(float, u);
}

// async global->LDS, 16 bytes/lane. LDS dest = wave-uniform base + lane*16.
static __device__ __forceinline__ void gld16(const u16* l, const u16* g) {
    __builtin_amdgcn_global_load_lds(
        (__attribute__((address_space(1))) void*)(g),
        (__attribute__((address_space(3))) void*)(l),
        16, 0, 0);
}

// f32 -> bf16, 8 elems/thread.
__global__ __launch_bounds__(256) void cvt_bf16(const float* __restrict__ s,
                                                u16* __restrict__ d, long n) {
    long i = ((long)blockIdx.x * 256 + threadIdx.x) * 8;
    if (i >= n) return;
    f32x4 a = *(const f32x4*)(s + i);
    f32x4 b = *(const f32x4*)(s + i + 4);
    short8 o;
    o[0] = (short)f2bf(a.x); o[1] = (short)f2bf(a.y);
    o[2] = (short)f2bf(a.z); o[3] = (short)f2bf(a.w);
    o[4] = (short)f2bf(b.x); o[5] = (short)f2bf(b.y);
    o[6] = (short)f2bf(b.z); o[7] = (short)f2bf(b.w);
    *(short8*)(d + i) = o;
}

// f32 [R][C] -> bf16 [C][R] (transpose + convert), 32x32 LDS tiles.
__global__ __launch_bounds__(256) void transpose_cvt(const float* __restrict__ in,
                                                     u16* __restrict__ out,
                                                     int R, int C) {
    __shared__ float t[32][33];
    const int c0 = blockIdx.x * 32;
    const int r0 = blockIdx.y * 32;
    const int x = threadIdx.x & 31;
    const int y = (threadIdx.x >> 5) * 4;
    #pragma unroll
    for (int i = 0; i < 4; i++)
        t[y + i][x] = in[(long)(r0 + y + i) * C + c0 + x];
    __syncthreads();
    #pragma unroll
    for (int i = 0; i < 4; i++)
        out[(long)(c0 + y + i) * R + r0 + x] = f2bf(t[x][y + i]);
}

// V slice of qkv (per batch [2048 s][1024 d], row stride 3072, col offset 2048)
// -> vt [b][1024 d][2048 s]. bf16 32x32 tile transpose.
__global__ __launch_bounds__(256) void transpose_v(const u16* __restrict__ qkv,
                                                   u16* __restrict__ vt) {
    __shared__ u16 t[32][33];
    const int b = blockIdx.z;
    const int s0 = blockIdx.y * 32;
    const int d0 = blockIdx.x * 32;
    const int x = threadIdx.x & 31;
    const int y = (threadIdx.x >> 5) * 4;
    const u16* src = qkv + (long)b * SEQ * 3072 + 2048;
    u16* dst = vt + (long)b * 1024 * SEQ;
    #pragma unroll
    for (int i = 0; i < 4; i++)
        t[y + i][x] = src[(long)(s0 + y + i) * 3072 + d0 + x];
    __syncthreads();
    #pragma unroll
    for (int i = 0; i < 4; i++)
        dst[(long)(d0 + y + i) * SEQ + s0 + x] = t[x][y + i];
}

// ============================ gemm256 ======================================
// 256x256 tile, BK=64, 512 threads = 8 waves (2M x 4N), per-wave 128x64 out
// = acc[8][4] f32x4. C[m][n] = sum_k A[m][k]*B[n][k] (B is [N][K] row-major).
//
// LDS 128 KiB: lds[2 slot][4 regions][8192 u16]. Regions (128 rows x 64 k,
// 16 KiB each): 0=A-lo (tile rows [0,128)), 1=A-hi ([128,256)),
// 2=B-lo (tile cols [0,128)), 3=B-hi ([128,256)). Region slot = tile&1.
// T2 swizzle: 16-B slot index ^= (region_row & 7); applied on the READ
// address and as pre-swizzled GLOBAL source col on the stage
// (global_load_lds writes linearly: wave base + lane*16).
//
// Schedule per K-tile t (quadrants (0,0),(0,1),(1,0),(1,1) via frag reuse;
// b0F=B-lo, b1F=B-hi held across phases; aF shared lo->hi):
//   q0: ds_read aF<-Alo(t) (8);                MFMA (0,0)=aF*b0F; BAR
//   q1: ds_read b1F<-Bhi(t) (4); STG Alo(t+2)+Blo(t+2);
//                                              MFMA (0,1)=aF*b1F; BAR
//   q2: ds_read aF<-Ahi(t) (8); STG Bhi(t+2);  MFMA (1,0)=aF*b0F; BAR
//   q3: STG Ahi(t+2); vmcnt(8); BAR; ds_read b0F<-Blo(t+1) (4);
//                                              MFMA (1,1)=aF*b1F   (no BAR)
// vmcnt ledger (8 loads/tile, issue order Alo,Blo@q1 Bhi@q2 Ahi@q3):
// at q3(t)'s vmcnt(8): outstanding = tile(t+1)'s 8 + tile(t+2)'s 8 = 16;
// drains exactly tile(t+1)'s 8, ages 4-7 phases (latency covered); leaves
// tile(t+2)'s 8 in flight. Every read follows its region's vmcnt+barrier;
// every overwrite (stage of X(t+2) into X(t)'s slot) is >=1 barrier after
// X(t)'s last ds_read (Alo read q0 < stage q1; Blo read mid-q3(t-1) <
// stage q1(t); Bhi read q1 < stage q2; Ahi read q2 < stage q3). All
// barriers are asm s_barrier + memory clobber so neither plain LDS reads
// nor global_load_lds can hoist across the drain point. Tail: stage tile
// clamped to t (same slot, identical data -- benign). Prologue stages
// tiles 0 and 1 in steady-state order, vmcnt(8) drains tile 0.
template<int EPI>
__global__ __launch_bounds__(512) void gemm256(
    const u16* __restrict__ Ap, long lda, long aBatch,
    const u16* __restrict__ Bp, long ldb, long bBatch,
    void* __restrict__ Cp, long ldc, long cBatch,
    const float* __restrict__ bias, float scale, int K, int nbx)
{
    __shared__ __attribute__((aligned(16))) u16 lds[2][4][8192];

    const int T = K >> 6;
    const int tid = threadIdx.x;
    const int lane = tid & 63;
    const int wave = tid >> 6;
    const int wm = wave >> 2;          // 0..1
    const int wn = wave & 3;           // 0..3
    const int m16 = lane & 15;
    const int quad = lane >> 4;
    const int b = blockIdx.z;

    // T1: bijective XCD swizzle (nwg % 8 == 0 for all launches here)
    const int nwg = gridDim.x;
    int wg = blockIdx.x;
    if ((nwg & 7) == 0)
        wg = (wg & 7) * (nwg >> 3) + (wg >> 3);
    const int bx = wg % nbx;
    const int by = wg / nbx;
    const long gm0 = (long)by * 256;
    const long gn0 = (long)bx * 256;

    const u16* A = Ap + (long)b * aBatch;
    const u16* B = Bp + (long)b * bBatch;

    // staging thread constants. Region row r = (i*8+wave)*8 + rl, r&7 == rl.
    const int rl = lane >> 3;                    // 0..7
    const int lsl = ((lane & 7) ^ rl) * 8;       // pre-swizzled src col (u16)
    const long aR = gm0 + wave * 8 + rl;         // + i*128 + h*64
    const long bR = gn0 + (wave >> 2) * 64 + (wave & 3) * 8 + rl; // + i*128 + h*32

#define STG_A(h, tt) do { \
    const int tc_ = ((tt) < T) ? (tt) : (tt) - 2; \
    const long kc_ = (long)(tc_ << 6); \
    const int sl_ = tc_ & 1; \
    gld16(&lds[sl_][h][wave * 512],       A + (aR + (h) * 64) * lda + kc_ + lsl); \
    gld16(&lds[sl_][h][(8 + wave) * 512], A + (aR + 128 + (h) * 64) * lda + kc_ + lsl); \
} while (0)
#define STG_B(h, tt) do { \
    const int tc_ = ((tt) < T) ? (tt) : (tt) - 2; \
    const long kc_ = (long)(tc_ << 6); \
    const int sl_ = tc_ & 1; \
    gld16(&lds[sl_][2 + (h)][wave * 512],       B + (bR + (h) * 32) * ldb + kc_ + lsl); \
    gld16(&lds[sl_][2 + (h)][(8 + wave) * 512], B + (bR + 128 + (h) * 32) * ldb + kc_ + lsl); \
} while (0)

    // read offsets (u16). A region row = wm*64 + mfl*16 + m16; B row =
    // wn*32 + nj*16 + m16; slot = ks*4+quad, swizzled ^= (m16&7).
    const int s0 = quad ^ (m16 & 7);
    const int aBase = (wm * 64 + m16) * 64;
    const int bBase = (wn * 32 + m16) * 64;
    const int aoff0 = aBase + s0 * 8, aoff1 = aBase + (s0 ^ 4) * 8;
    const int boff0 = bBase + s0 * 8, boff1 = bBase + (s0 ^ 4) * 8;

    short8 aF[4][2], b0F[2][2], b1F[2][2];
    f32x4 acc[8][4];
    #pragma unroll
    for (int mi = 0; mi < 8; mi++)
        #pragma unroll
        for (int ni = 0; ni < 4; ni++)
            acc[mi][ni] = (f32x4){0.f, 0.f, 0.f, 0.f};

#define LD_A(sl, h) do { \
    const u16* p_ = &lds[sl][h][0]; \
    _Pragma("unroll") \
    for (int mfl_ = 0; mfl_ < 4; ++mfl_) { \
        aF[mfl_][0] = *(const short8*)(p_ + aoff0 + mfl_ * 1024); \
        aF[mfl_][1] = *(const short8*)(p_ + aoff1 + mfl_ * 1024); \
    } \
} while (0)
#define LD_B(sl, h, BF) do { \
    const u16* p_ = &lds[sl][2 + (h)][0]; \
    _Pragma("unroll") \
    for (int nj_ = 0; nj_ < 2; ++nj_) { \
        BF[nj_][0] = *(const short8*)(p_ + boff0 + nj_ * 1024); \
        BF[nj_][1] = *(const short8*)(p_ + boff1 + nj_ * 1024); \
    } \
} while (0)
#define MFMAQ(mh, nh, BF) do { \
    _Pragma("unroll") \
    for (int mi_ = 0; mi_ < 4; ++mi_) \
    _Pragma("unroll") \
    for (int nj_ = 0; nj_ < 2; ++nj_) { \
        acc[(mh)*4+mi_][(nh)*2+nj_] = __builtin_amdgcn_mfma_f32_16x16x32_bf16( \
            aF[mi_][0], BF[nj_][0], acc[(mh)*4+mi_][(nh)*2+nj_], 0, 0, 0); \
        acc[(mh)*4+mi_][(nh)*2+nj_] = __builtin_amdgcn_mfma_f32_16x16x32_bf16( \
            aF[mi_][1], BF[nj_][1], acc[(mh)*4+mi_][(nh)*2+nj_], 0, 0, 0); \
    } \
} while (0)
#define BAR() asm volatile("s_barrier" ::: "memory")
#define VM8() asm volatile("s_waitcnt vmcnt(8)" ::: "memory")
#define SETP(p) __builtin_amdgcn_s_setprio(p)

    // prologue: tiles 0 and 1 staged in steady-state issue order
    STG_A(0, 0); STG_B(0, 0); STG_B(1, 0); STG_A(1, 0);
    STG_A(0, 1); STG_B(0, 1); STG_B(1, 1); STG_A(1, 1);
    VM8();                   // drains tile-0's 8 loads; tile-1's in flight
    BAR();
    LD_B(0, 0, b0F);         // bLo(0)

    for (int t = 0; t < T; ++t) {
        const int buf = t & 1, nb = buf ^ 1;
        // ---- q0: (0,0) = aLo x bLo
        LD_A(buf, 0);
        SETP(1); MFMAQ(0, 0, b0F); SETP(0);
        BAR();
        // ---- q1: (0,1) = aLo x bHi
        LD_B(buf, 1, b1F);
        STG_A(0, t + 2);
        STG_B(0, t + 2);
        SETP(1); MFMAQ(0, 1, b1F); SETP(0);
        BAR();
        // ---- q2: (1,0) = aHi x bLo
        LD_A(buf, 1);
        STG_B(1, t + 2);
        SETP(1); MFMAQ(1, 0, b0F); SETP(0);
        BAR();
        // ---- q3: (1,1) = aHi x bHi; drain tile t+1; prefetch bLo(t+1)
        STG_A(1, t + 2);
        VM8();
        BAR();
        LD_B(nb, 0, b0F);
        SETP(1); MFMAQ(1, 1, b1F); SETP(0);
        // no barrier at tile boundary: q0's LD_A reads a region guaranteed
        // by this VM8+BAR; aF WAR handled by in-order wave issue.
    }

    // C-write. Frag (mi,ni): rows gm0+wm*128+(mi>>2)*64+(mi&3)*16+quad*4+r,
    // col gn0+wn*64+(ni>>1)*32+(ni&1)*16+m16.
    const long row0 = gm0 + wm * 128 + quad * 4;
    if (EPI == 0 || EPI == 1) {
        u16* C = (u16*)Cp + (long)b * cBatch;
        #pragma unroll
        for (int ni = 0; ni < 4; ++ni) {
            const long col = gn0 + wn * 64 + (ni >> 1) * 32 + (ni & 1) * 16 + m16;
            const float bv = (EPI == 0 && bias) ? bias[col] : 0.f;
            #pragma unroll
            for (int mi = 0; mi < 8; ++mi) {
                const long rb = row0 + (mi >> 2) * 64 + (mi & 3) * 16;
                #pragma unroll
                for (int r = 0; r < 4; ++r) {
                    const float vv = (EPI == 1) ? acc[mi][ni][r] * scale
                                                : acc[mi][ni][r] + bv;
                    C[(rb + r) * ldc + col] = f2bf(vv);
                }
            }
        }
    } else {
        float* C = (float*)Cp + (long)b * cBatch;
        #pragma unroll
        for (int ni = 0; ni < 4; ++ni) {
            const long col = gn0 + wn * 64 + (ni >> 1) * 32 + (ni & 1) * 16 + m16;
            const float bv = bias ? bias[col] : 0.f;
            #pragma unroll
            for (int mi = 0; mi < 8; ++mi) {
                const long rb = row0 + (mi >> 2) * 64 + (mi & 3) * 16;
                #pragma unroll
                for (int r = 0; r < 4; ++r)
                    C[(rb + r) * ldc + col] = acc[mi][ni][r] + bv;
            }
        }
    }
#undef STG_A
#undef STG_B
#undef LD_A
#undef LD_B
#undef MFMAQ
#undef BAR
#undef VM8
#undef SETP
}

// bf16 MFMA GEMM, 128x128 tile, BK=64 (kept for K4/K5 whose 256^2 grids
// would only fill half the CUs at 1 block/CU).
template<int EPI>
__global__ __launch_bounds__(256) void gemm128(
    const u16* __restrict__ Ap, long lda, long aBatch,
    const u16* __restrict__ Bp, long ldb, long bBatch,
    void* __restrict__ Cp, long ldc, long cBatch,
    const float* __restrict__ bias,
    float scale, int K)
{
    __shared__ __attribute__((aligned(16))) u16 As[128 * 64];
    __shared__ __attribute__((aligned(16))) u16 Bs[128 * 64];

    const int tid = threadIdx.x;
    const int lane = tid & 63;
    const int wave = tid >> 6;
    const int b = blockIdx.z;
    const long m0 = (long)blockIdx.y * 128;
    const long n0 = (long)blockIdx.x * 128;

    const u16* A = Ap + (long)b * aBatch;
    const u16* B = Bp + (long)b * bBatch;

    const int wm = (wave >> 1) * 64;
    const int wn = (wave & 1) * 64;
    const int m16 = lane & 15;
    const int quad = lane >> 4;

    const int srow = lane >> 3;
    const int skk = (lane & 7) * 8;

    f32x4 acc[4][4];
    #pragma unroll
    for (int mi = 0; mi < 4; mi++)
        #pragma unroll
        for (int ni = 0; ni < 4; ni++)
            acc[mi][ni] = (f32x4){0.f, 0.f, 0.f, 0.f};

    for (int k0 = 0; k0 < K; k0 += 64) {
        #pragma unroll
        for (int c = 0; c < 4; c++) {
            const int r = wave * 32 + c * 8 + srow;
            gld16(As + (wave * 4 + c) * 512, A + (m0 + r) * lda + k0 + skk);
            gld16(Bs + (wave * 4 + c) * 512, B + (n0 + r) * ldb + k0 + skk);
        }
        __syncthreads();

        #pragma unroll
        for (int ks = 0; ks < 2; ks++) {
            short8 af[4], bf[4];
            #pragma unroll
            for (int i = 0; i < 4; i++) {
                af[i] = *(const short8*)&As[(wm + i * 16 + m16) * 64 + ks * 32 + quad * 8];
                bf[i] = *(const short8*)&Bs[(wn + i * 16 + m16) * 64 + ks * 32 + quad * 8];
            }
            #pragma unroll
            for (int mi = 0; mi < 4; mi++)
                #pragma unroll
                for (int ni = 0; ni < 4; ni++)
                    acc[mi][ni] = __builtin_amdgcn_mfma_f32_16x16x32_bf16(
                        af[mi], bf[ni], acc[mi][ni], 0, 0, 0);
        }
        __syncthreads();
    }

    const long row_base = m0 + wm + quad * 4;
    if (EPI == 0) {
        u16* C = (u16*)Cp + (long)b * cBatch;
        #pragma unroll
        for (int ni = 0; ni < 4; ni++) {
            const long col = n0 + wn + ni * 16 + m16;
            const float bv = bias ? bias[col] : 0.f;
            #pragma unroll
            for (int mi = 0; mi < 4; mi++)
                #pragma unroll
                for (int r = 0; r < 4; r++)
                    C[(row_base + mi * 16 + r) * ldc + col] = f2bf(acc[mi][ni][r] + bv);
        }
    } else if (EPI == 1) {
        u16* C = (u16*)Cp + (long)b * cBatch;
        #pragma unroll
        for (int ni = 0; ni < 4; ni++) {
            const long col = n0 + wn + ni * 16 + m16;
            #pragma unroll
            for (int mi = 0; mi < 4; mi++)
                #pragma unroll
                for (int r = 0; r < 4; r++)
                    C[(row_base + mi * 16 + r) * ldc + col] = f2bf(acc[mi][ni][r] * scale);
        }
    } else {
        float* C = (float*)Cp + (long)b * cBatch;
        #pragma unroll
        for (int ni = 0; ni < 4; ni++) {
            const long col = n0 + wn + ni * 16 + m16;
            const float bv = bias ? bias[col] : 0.f;
            #pragma unroll
            for (int mi = 0; mi < 4; mi++)
                #pragma unroll
                for (int r = 0; r < 4; r++)
                    C[(row_base + mi * 16 + r) * ldc + col] = acc[mi][ni][r] + bv;
        }
    }
}

// in-place masked row softmax over 2048 bf16 (f32 math). 1 block per row.
// mask==0 -> score := 1e-10 (applied here in f32; coalesced uint4 reads).
__global__ __launch_bounds__(256) void softmax2048(u16* __restrict__ S,
                                                   const int* __restrict__ mask) {
    const long row = blockIdx.x;
    u16* p = S + row * SEQ;
    const int* mrow = mask + row * SEQ;
    const int tid = threadIdx.x;

    short8 v = *(const short8*)(p + tid * 8);
    uint4 mw0 = *(const uint4*)(mrow + tid * 8);
    uint4 mw1 = *(const uint4*)(mrow + tid * 8 + 4);
    const unsigned int* mwv = (const unsigned int*)&mw0;

    float f[8];
    #pragma unroll
    for (int j = 0; j < 8; j++) {
        const unsigned int mv = (j < 4) ? mwv[j] : ((const unsigned int*)&mw1)[j - 4];
        f[j] = (mv == 0u) ? 1e-10f : bf2f((u16)v[j]);
    }

    float m = f[0];
    #pragma unroll
    for (int j = 1; j < 8; j++) m = fmaxf(m, f[j]);
    #pragma unroll
    for (int i = 1; i < 64; i <<= 1) m = fmaxf(m, __shfl_xor(m, i));

    __shared__ float redm[4], reds[4];
    if ((tid & 63) == 0) redm[tid >> 6] = m;
    __syncthreads();
    m = fmaxf(fmaxf(redm[0], redm[1]), fmaxf(redm[2], redm[3]));

    float e[8], s = 0.f;
    #pragma unroll
    for (int j = 0; j < 8; j++) { e[j] = __expf(f[j] - m); s += e[j]; }
    #pragma unroll
    for (int i = 1; i < 64; i <<= 1) s += __shfl_xor(s, i);
    if ((tid & 63) == 0) reds[tid >> 6] = s;
    __syncthreads();
    s = reds[0] + reds[1] + reds[2] + reds[3];

    const float inv = 1.f / s;
    short8 o;
    #pragma unroll
    for (int j = 0; j < 8; j++) o[j] = (short)f2bf(e[j] * inv);
    *(short8*)(p + tid * 8) = o;
}

extern "C" void kernel_launch(void* const* d_in, const int* in_sizes, int n_in,
                              void* d_out, int out_size, void* d_ws, size_t ws_size,
                              hipStream_t stream) {
    const float* x    = (const float*)d_in[0];
    const int*   mask = (const int*)d_in[1];
    const float* Wqkv = (const float*)d_in[2];
    const float* bqkv = (const float*)d_in[3];
    const float* Wout = (const float*)d_in[4];
    const float* bout = (const float*)d_in[5];
    float* out = (float*)d_out;

    char* ws = (char*)d_ws;
    // ws layout, total 102,760,448 bytes:
    //   [0,        16777216) xh  bf16 [8192][1024]          (cvt -> K1)
    //   [16777216, 23068672) wqt bf16 [3072][1024]          (cvt -> K1)
    //   [0,        33554432) sc  bf16 [4][2048][2048]       (K2 -> K4; xh,wqt dead)
    //   [33554432, 35651584) wot bf16 [1024][1024]          (cvt -> K5)
    //   [35651584, 85983232) qkv bf16 [8192][3072]          (K1 -> K2)
    //   [35651584, 52428800) attn bf16 [8192][1024]         (K4 -> K5; qkv dead)
    //   [85983232,102760448) vt  bf16 [4][1024][2048]       (transpose_v -> K4)
    u16* xh   = (u16*)(ws + 0);
    u16* wqt  = (u16*)(ws + 16777216);
    u16* sc   = (u16*)(ws + 0);
    u16* wot  = (u16*)(ws + 33554432);
    u16* qkv  = (u16*)(ws + 35651584);
    u16* attn = (u16*)(ws + 35651584);
    u16* vt   = (u16*)(ws + 85983232);

    cvt_bf16<<<4096, 256, 0, stream>>>(x, xh, 8388608);
    transpose_cvt<<<dim3(96, 32), 256, 0, stream>>>(Wqkv, wqt, 1024, 3072);
    transpose_cvt<<<dim3(32, 32), 256, 0, stream>>>(Wout, wot, 1024, 1024);

    // K1: qkv = x @ Wqkv + bqkv   (M=8192, N=3072, K=1024), bf16 out.
    // 256^2 deep-pipeline: grid 12x32 = 384 wgs, nbx = 12.
    gemm256<0><<<dim3(384, 1, 1), 512, 0, stream>>>(
        xh, 1024, 0, wqt, 1024, 0, qkv, 3072, 0, bqkv, 1.f, 1024, 12);

    // V slice -> vt [b][d][s]
    transpose_v<<<dim3(32, 64, NB), 256, 0, stream>>>(qkv, vt);

    // K2: sc[b] = (Q[b] @ K[b]^T)/32   (M=N=2048, K=1024), bf16 out.
    // 8x8 = 64 wgs/batch x 4 = 256 = exactly 1 block/CU.
    gemm256<1><<<dim3(64, 1, NB), 512, 0, stream>>>(
        qkv, 3072, (long)SEQ * 3072, qkv + 1024, 3072, (long)SEQ * 3072,
        sc, SEQ, (long)SEQ * SEQ, nullptr, 0.03125f, 1024, 8);

    // K3: masked softmax rows (mask==0 -> 1e-10, f32 math, bf16 storage)
    softmax2048<<<dim3(NB * SEQ), 256, 0, stream>>>(sc, mask);

    // K4: attn[b] = P[b] @ V[b]   (M=2048, N=1024, K=2048), bf16 out
    gemm128<0><<<dim3(8, 16, NB), 256, 0, stream>>>(
        sc, SEQ, (long)SEQ * SEQ, vt, SEQ, (long)1024 * SEQ,
        attn, 1024, (long)SEQ * 1024, nullptr, 1.f, 2048);

    // K5: out = attn @ Wout + bout   (M=8192, N=1024, K=1024), f32 out
    gemm128<2><<<dim3(8, 64, 1), 256, 0, stream>>>(
        attn, 1024, 0, wot, 1024, 0, out, 1024, 0, bout, 1.f, 1024);
}